// Round 1
// baseline (143.308 us; speedup 1.0000x reference)
//
#include <hip/hip_runtime.h>
#include <hip/hip_bf16.h>
#include <cstdint>

// Problem dims (fixed by reference)
#define B_TOK 4096
#define DDIM  2048
#define KR    512
#define NE    8

using f32x4  = __attribute__((ext_vector_type(4))) float;
using short8 = __attribute__((ext_vector_type(8))) short;
using u16 = unsigned short;

__device__ inline u16 f2bf(float f) {
    union { float f; uint32_t u; } x; x.f = f;
    uint32_t u = x.u;
    return (u16)((u + 0x7fffu + ((u >> 16) & 1u)) >> 16);  // RNE
}

__device__ inline void gload_lds16(const u16* g, u16* l) {
    __builtin_amdgcn_global_load_lds(
        (const __attribute__((address_space(1))) void*)g,
        (__attribute__((address_space(3))) void*)l, 16, 0, 0);
}

// ---------------- conversion: f32 2D block -> bf16 2D block ----------------
__global__ void cvt_copy2d(const float* __restrict__ src, u16* __restrict__ dst,
                           int rows, int cols4, int src_ld, int dst_ld) {
    int total = rows * cols4;
    for (int i = blockIdx.x * blockDim.x + threadIdx.x; i < total;
         i += gridDim.x * blockDim.x) {
        int r = i / cols4, c = i - r * cols4;
        float4 val = *((const float4*)(src + (size_t)r * src_ld) + c);
        ushort4 o;
        o.x = f2bf(val.x); o.y = f2bf(val.y); o.z = f2bf(val.z); o.w = f2bf(val.w);
        *((ushort4*)(dst + (size_t)r * dst_ld) + c) = o;
    }
}

// ---------------- transpose U (D,K) f32 -> U^T (K,D) bf16 ----------------
__global__ void transpose_cvt(const float* __restrict__ src, u16* __restrict__ dst,
                              int src_cols /*K*/, int dst_ld /*D*/) {
    __shared__ float tile[32][33];
    int c0 = blockIdx.x * 32;   // src col (k)
    int r0 = blockIdx.y * 32;   // src row (d)
    int tx = threadIdx.x, ty = threadIdx.y; // 32 x 8
    #pragma unroll
    for (int j = 0; j < 32; j += 8)
        tile[ty + j][tx] = src[(size_t)(r0 + ty + j) * src_cols + c0 + tx];
    __syncthreads();
    #pragma unroll
    for (int j = 0; j < 32; j += 8)
        dst[(size_t)(c0 + ty + j) * dst_ld + r0 + tx] = f2bf(tile[tx][ty + j]);
}

// ---------------- router: s=r.W1, g=softmax(s*W2), m = (g.lam) * t ----------------
__global__ __launch_bounds__(256)
void router_kernel(const float* __restrict__ rt, const float* __restrict__ W1,
                   const float* __restrict__ W2, const float* __restrict__ lam,
                   u16* __restrict__ Aaug) {
    int b = blockIdx.x;
    int tid = threadIdx.x;
    const float* r = rt + (size_t)b * 1024;

    float p = r[tid] * W1[tid] + r[tid + 256] * W1[tid + 256];
    #pragma unroll
    for (int o = 32; o > 0; o >>= 1) p += __shfl_down(p, o);
    __shared__ float sp[4];
    __shared__ float sbc;
    if ((tid & 63) == 0) sp[tid >> 6] = p;
    __syncthreads();
    if (tid == 0) sbc = sp[0] + sp[1] + sp[2] + sp[3];
    __syncthreads();
    float s = sbc;

    float g[NE]; float mx = -1e30f;
    #pragma unroll
    for (int e = 0; e < NE; e++) { g[e] = s * W2[e]; mx = fmaxf(mx, g[e]); }
    float den = 0.f;
    #pragma unroll
    for (int e = 0; e < NE; e++) { g[e] = expf(g[e] - mx); den += g[e]; }
    float inv = 1.0f / den;

    for (int kk = tid; kk < KR; kk += 256) {
        float mu = 0.f;
        #pragma unroll
        for (int e = 0; e < NE; e++) mu += g[e] * lam[e * KR + kk];
        float m = mu * inv * r[512 + kk];
        Aaug[(size_t)b * 2560 + 2048 + kk] = f2bf(m);
    }
}

// ---------------- bf16 B^T GEMM: C[m,n] = sum_k A[m,k]*B[n,k] (+ (1+v[n]) scale) ----
template<bool HAS_V>
__global__ __launch_bounds__(256, 2)
void gemm_bt128(const u16* __restrict__ A, const u16* __restrict__ Bm,
                float* __restrict__ C, const float* __restrict__ v,
                int N, int Kc, int lda, int ldb) {
    __shared__ u16 sA[128 * 32];
    __shared__ u16 sB[128 * 32];
    int tid = threadIdx.x;
    int wid = tid >> 6, lane = tid & 63;
    int wm = wid >> 1, wn = wid & 1;
    int row0 = blockIdx.y * 128;
    int col0 = blockIdx.x * 128;
    const int l15 = lane & 15, l4 = lane >> 4;

    f32x4 acc[4][4] = {};

    // staging: per issue j (0/1), thread covers row j*64 + tid/4, col (tid&3)*8
    int srow = tid >> 2;
    int scol = (tid & 3) * 8;
    const u16* gA0 = A + (size_t)(row0 + srow) * lda + scol;
    const u16* gA1 = A + (size_t)(row0 + 64 + srow) * lda + scol;
    const u16* gB0 = Bm + (size_t)(col0 + srow) * ldb + scol;
    const u16* gB1 = Bm + (size_t)(col0 + 64 + srow) * ldb + scol;
    u16* lA0 = sA + wid * 512;          // wave-uniform LDS bases
    u16* lA1 = sA + 2048 + wid * 512;
    u16* lB0 = sB + wid * 512;
    u16* lB1 = sB + 2048 + wid * 512;

    for (int kt = 0; kt < Kc; kt += 32) {
        __syncthreads();
        gload_lds16(gA0 + kt, lA0);
        gload_lds16(gA1 + kt, lA1);
        gload_lds16(gB0 + kt, lB0);
        gload_lds16(gB1 + kt, lB1);
        __syncthreads();

        short8 af[4], bfr[4];
        #pragma unroll
        for (int mf = 0; mf < 4; mf++)
            af[mf] = *(const short8*)(sA + (wm * 64 + mf * 16 + l15) * 32 + l4 * 8);
        #pragma unroll
        for (int nf = 0; nf < 4; nf++)
            bfr[nf] = *(const short8*)(sB + (wn * 64 + nf * 16 + l15) * 32 + l4 * 8);
        #pragma unroll
        for (int mf = 0; mf < 4; mf++)
            #pragma unroll
            for (int nf = 0; nf < 4; nf++)
                acc[mf][nf] = __builtin_amdgcn_mfma_f32_16x16x32_bf16(
                    af[mf], bfr[nf], acc[mf][nf], 0, 0, 0);
    }

    #pragma unroll
    for (int nf = 0; nf < 4; nf++) {
        int col = col0 + wn * 64 + nf * 16 + l15;
        float sc = HAS_V ? (1.0f + v[col]) : 1.0f;
        #pragma unroll
        for (int mf = 0; mf < 4; mf++) {
            int row = row0 + wm * 64 + mf * 16 + l4 * 4;
            #pragma unroll
            for (int r2 = 0; r2 < 4; r2++)
                C[(size_t)(row + r2) * N + col] = acc[mf][nf][r2] * sc;
        }
    }
}

extern "C" void kernel_launch(void* const* d_in, const int* in_sizes, int n_in,
                              void* d_out, int out_size, void* d_ws, size_t ws_size,
                              hipStream_t stream) {
    const float* x   = (const float*)d_in[0];
    const float* W   = (const float*)d_in[1];
    const float* U   = (const float*)d_in[2];
    const float* V   = (const float*)d_in[3];
    const float* lam = (const float*)d_in[4];
    const float* v   = (const float*)d_in[5];
    const float* W1  = (const float*)d_in[6];
    const float* W2  = (const float*)d_in[7];
    float* out = (float*)d_out;

    char* ws = (char*)d_ws;
    u16*   Aaug = (u16*)ws;                               // 4096 x 2560 bf16 (x | m)
    u16*   BigB = (u16*)(ws + 20971520);                  // 2048 x 2560 bf16 (W | U)
    u16*   UVT  = (u16*)(ws + 31457280);                  // 1024 x 2048 bf16 (U^T ; V)
    float* rt   = (float*)(ws + 35651584);                // 4096 x 1024 f32 (r | t)

    // conversions (independent)
    cvt_copy2d<<<2048, 256, 0, stream>>>(x, Aaug, 4096, 512, 2048, 2560);
    cvt_copy2d<<<2048, 256, 0, stream>>>(W, BigB, 2048, 512, 2048, 2560);
    cvt_copy2d<<<1024, 256, 0, stream>>>(U, BigB + 2048, 2048, 128, 512, 2560);
    cvt_copy2d<<<2048, 256, 0, stream>>>(V, UVT + (size_t)512 * 2048, 512, 512, 2048, 2048);
    transpose_cvt<<<dim3(16, 64), dim3(32, 8), 0, stream>>>(U, UVT, 512, 2048);

    // GEMM1: rt(4096x1024) = xb @ [U^T;V]^T, K=2048
    gemm_bt128<false><<<dim3(8, 32), 256, 0, stream>>>(Aaug, UVT, rt, nullptr,
                                                       1024, 2048, 2560, 2048);
    // router -> m into Aaug[:, 2048:2560]
    router_kernel<<<4096, 256, 0, stream>>>(rt, W1, W2, lam, Aaug);

    // GEMM2: out(4096x2048) = [xb|m] @ [W|U]^T, K=2560, epilogue *(1+v)
    gemm_bt128<true><<<dim3(16, 32), 256, 0, stream>>>(Aaug, BigB, out, v,
                                                       2048, 2560, 2560, 2560);
}

// Round 2
// 111.137 us; speedup vs baseline: 1.2895x; 1.2895x over previous
//
#include <hip/hip_runtime.h>
#include <hip/hip_bf16.h>
#include <cstdint>

#define B_TOK 4096
#define DDIM  2048
#define KR    512
#define NE    8

using f32x4  = __attribute__((ext_vector_type(4))) float;
using short8 = __attribute__((ext_vector_type(8))) short;
using u16 = unsigned short;

__device__ inline u16 f2bf(float f) {
    union { float f; uint32_t u; } x; x.f = f;
    uint32_t u = x.u;
    return (u16)((u + 0x7fffu + ((u >> 16) & 1u)) >> 16);  // RNE
}

__device__ inline void gload_lds16(const u16* g, u16* l) {
    __builtin_amdgcn_global_load_lds(
        (const __attribute__((address_space(1))) void*)g,
        (__attribute__((address_space(3))) void*)l, 16, 0, 0);
}

// ---------------- conversion: f32 2D block -> bf16 2D block ----------------
__global__ void cvt_copy2d(const float* __restrict__ src, u16* __restrict__ dst,
                           int rows, int cols4, int src_ld, int dst_ld) {
    int total = rows * cols4;
    for (int i = blockIdx.x * blockDim.x + threadIdx.x; i < total;
         i += gridDim.x * blockDim.x) {
        int r = i / cols4, c = i - r * cols4;
        float4 val = *((const float4*)(src + (size_t)r * src_ld) + c);
        ushort4 o;
        o.x = f2bf(val.x); o.y = f2bf(val.y); o.z = f2bf(val.z); o.w = f2bf(val.w);
        *((ushort4*)(dst + (size_t)r * dst_ld) + c) = o;
    }
}

// ---------------- transpose U (D,K) f32 -> U^T (K,D) bf16 ----------------
__global__ void transpose_cvt(const float* __restrict__ src, u16* __restrict__ dst,
                              int src_cols /*K*/, int dst_ld /*D*/) {
    __shared__ float tile[32][33];
    int c0 = blockIdx.x * 32;
    int r0 = blockIdx.y * 32;
    int tx = threadIdx.x, ty = threadIdx.y; // 32 x 8
    #pragma unroll
    for (int j = 0; j < 32; j += 8)
        tile[ty + j][tx] = src[(size_t)(r0 + ty + j) * src_cols + c0 + tx];
    __syncthreads();
    #pragma unroll
    for (int j = 0; j < 32; j += 8)
        dst[(size_t)(c0 + ty + j) * dst_ld + r0 + tx] = f2bf(tile[tx][ty + j]);
}

// ---------------- router ----------------
__global__ __launch_bounds__(256)
void router_kernel(const float* __restrict__ rt, const float* __restrict__ W1,
                   const float* __restrict__ W2, const float* __restrict__ lam,
                   u16* __restrict__ Aaug) {
    int b = blockIdx.x;
    int tid = threadIdx.x;
    const float* r = rt + (size_t)b * 1024;

    float p = r[tid] * W1[tid] + r[tid + 256] * W1[tid + 256];
    #pragma unroll
    for (int o = 32; o > 0; o >>= 1) p += __shfl_down(p, o);
    __shared__ float sp[4];
    __shared__ float sbc;
    if ((tid & 63) == 0) sp[tid >> 6] = p;
    __syncthreads();
    if (tid == 0) sbc = sp[0] + sp[1] + sp[2] + sp[3];
    __syncthreads();
    float s = sbc;

    float g[NE]; float mx = -1e30f;
    #pragma unroll
    for (int e = 0; e < NE; e++) { g[e] = s * W2[e]; mx = fmaxf(mx, g[e]); }
    float den = 0.f;
    #pragma unroll
    for (int e = 0; e < NE; e++) { g[e] = expf(g[e] - mx); den += g[e]; }
    float inv = 1.0f / den;

    for (int kk = tid; kk < KR; kk += 256) {
        float mu = 0.f;
        #pragma unroll
        for (int e = 0; e < NE; e++) mu += g[e] * lam[e * KR + kk];
        float m = mu * inv * r[512 + kk];
        Aaug[(size_t)b * 2560 + 2048 + kk] = f2bf(m);
    }
}

// -------- bf16 B^T GEMM, BK=64, LDS double-buffer + prefetch, T2 swizzle ----
// C[m,n] = sum_k A[m,k]*B[n,k]; optional (1+v[n]) epilogue scale.
// LDS tile layout: rows of 64 u16 (128 B) split in 8 chunks of 8 u16 (16 B);
// chunk is XOR-swizzled by (row&7) on BOTH the global source (staging) and
// the ds_read side (rule 21: global_load_lds dest must stay linear).
template<int BM, int BN, int WGM, int WGN, bool HAS_V>
__global__ __launch_bounds__(256, 2)
void gemm_db(const u16* __restrict__ A, const u16* __restrict__ Bm,
             float* __restrict__ C, const float* __restrict__ v,
             int N, int Kc, int lda, int ldb, int nbx) {
    constexpr int MF = BM / (WGM * 16);
    constexpr int NF = BN / (WGN * 16);
    constexpr int ISSA = BM / 32;   // 4KB staging issues per A tile
    constexpr int ISSB = BN / 32;
    __shared__ u16 sA[2 * BM * 64];
    __shared__ u16 sB[2 * BN * 64];

    const int tid = threadIdx.x;
    const int wid = tid >> 6, lane = tid & 63;
    const int l15 = lane & 15, l4 = lane >> 4;
    const int wm = wid / WGN, wn = wid % WGN;

    // bijective XCD swizzle (nwg % 8 == 0 by construction), row-chunked:
    // each XCD owns contiguous ids -> few A row-panels -> L2 locality.
    const int nwg = gridDim.x;
    const int id = (blockIdx.x & 7) * (nwg >> 3) + (blockIdx.x >> 3);
    const int row0 = (id / nbx) * BM;
    const int col0 = (id % nbx) * BN;

    // staging addressing: thread t covers (row = i*32 + t/8, chunk = t&7);
    // pre-swizzled source chunk = (t&7) ^ (row&7); i*32 doesn't change row&7.
    const int srow = tid >> 3;
    const int scol = ((tid & 7) ^ (srow & 7)) << 3;
    const u16* gA = A + (size_t)(row0 + srow) * lda + scol;
    const u16* gB = Bm + (size_t)(col0 + srow) * ldb + scol;

    f32x4 acc[MF][NF] = {};
    const int nt = Kc >> 6;

    // prologue: stage tile 0 into buf 0
    #pragma unroll
    for (int i = 0; i < ISSA; i++)
        gload_lds16(gA + (size_t)i * 32 * lda, sA + i * 2048 + wid * 512);
    #pragma unroll
    for (int i = 0; i < ISSB; i++)
        gload_lds16(gB + (size_t)i * 32 * ldb, sB + i * 2048 + wid * 512);
    __syncthreads();   // implicit vmcnt(0) drain

    for (int t = 0; t < nt; ++t) {
        const int cur = t & 1;
        if (t + 1 < nt) {   // issue next-tile loads BEFORE compute (T3 minimum)
            const int nxt = cur ^ 1;
            const u16* gAk = gA + (size_t)(t + 1) * 64;
            const u16* gBk = gB + (size_t)(t + 1) * 64;
            #pragma unroll
            for (int i = 0; i < ISSA; i++)
                gload_lds16(gAk + (size_t)i * 32 * lda,
                            sA + nxt * BM * 64 + i * 2048 + wid * 512);
            #pragma unroll
            for (int i = 0; i < ISSB; i++)
                gload_lds16(gBk + (size_t)i * 32 * ldb,
                            sB + nxt * BN * 64 + i * 2048 + wid * 512);
        }
        const u16* a0 = sA + cur * BM * 64;
        const u16* b0 = sB + cur * BN * 64;
        #pragma unroll
        for (int kc = 0; kc < 8; kc += 4) {   // two K=32 sub-steps
            short8 af[MF], bv[NF];
            #pragma unroll
            for (int mf = 0; mf < MF; mf++) {
                int row = wm * MF * 16 + mf * 16 + l15;
                int ch = (kc + l4) ^ (row & 7);
                af[mf] = *(const short8*)(a0 + row * 64 + ch * 8);
            }
            #pragma unroll
            for (int nf = 0; nf < NF; nf++) {
                int row = wn * NF * 16 + nf * 16 + l15;
                int ch = (kc + l4) ^ (row & 7);
                bv[nf] = *(const short8*)(b0 + row * 64 + ch * 8);
            }
            #pragma unroll
            for (int mf = 0; mf < MF; mf++)
                #pragma unroll
                for (int nf = 0; nf < NF; nf++)
                    acc[mf][nf] = __builtin_amdgcn_mfma_f32_16x16x32_bf16(
                        af[mf], bv[nf], acc[mf][nf], 0, 0, 0);
        }
        __syncthreads();   // drains next-tile loads + protects buffer reuse
    }

    #pragma unroll
    for (int nf = 0; nf < NF; nf++) {
        int col = col0 + wn * NF * 16 + nf * 16 + l15;
        float sc = HAS_V ? (1.0f + v[col]) : 1.0f;
        #pragma unroll
        for (int mf = 0; mf < MF; mf++) {
            int row = row0 + wm * MF * 16 + mf * 16 + l4 * 4;
            #pragma unroll
            for (int r2 = 0; r2 < 4; r2++)
                C[(size_t)(row + r2) * N + col] = acc[mf][nf][r2] * sc;
        }
    }
}

extern "C" void kernel_launch(void* const* d_in, const int* in_sizes, int n_in,
                              void* d_out, int out_size, void* d_ws, size_t ws_size,
                              hipStream_t stream) {
    const float* x   = (const float*)d_in[0];
    const float* W   = (const float*)d_in[1];
    const float* U   = (const float*)d_in[2];
    const float* V   = (const float*)d_in[3];
    const float* lam = (const float*)d_in[4];
    const float* v   = (const float*)d_in[5];
    const float* W1  = (const float*)d_in[6];
    const float* W2  = (const float*)d_in[7];
    float* out = (float*)d_out;

    char* ws = (char*)d_ws;
    u16*   Aaug = (u16*)ws;                               // 4096 x 2560 bf16 (x | m)
    u16*   BigB = (u16*)(ws + 20971520);                  // 2048 x 2560 bf16 (W | U)
    u16*   UVT  = (u16*)(ws + 31457280);                  // 1024 x 2048 bf16 (U^T ; V)
    float* rt   = (float*)(ws + 35651584);                // 4096 x 1024 f32 (r | t)

    cvt_copy2d<<<2048, 256, 0, stream>>>(x, Aaug, 4096, 512, 2048, 2560);
    cvt_copy2d<<<2048, 256, 0, stream>>>(W, BigB, 2048, 512, 2048, 2560);
    cvt_copy2d<<<1024, 256, 0, stream>>>(U, BigB + 2048, 2048, 128, 512, 2560);
    cvt_copy2d<<<2048, 256, 0, stream>>>(V, UVT + (size_t)512 * 2048, 512, 512, 2048, 2048);
    transpose_cvt<<<dim3(16, 64), dim3(32, 8), 0, stream>>>(U, UVT, 512, 2048);

    // GEMM1: rt(4096x1024) = xb @ [U^T;V]^T, K=2048. BN=64 -> 512 blocks.
    gemm_db<128, 64, 4, 1, false><<<512, 256, 0, stream>>>(
        Aaug, UVT, rt, nullptr, 1024, 2048, 2560, 2048, 16);

    router_kernel<<<4096, 256, 0, stream>>>(rt, W1, W2, lam, Aaug);

    // GEMM2: out(4096x2048) = [xb|m] @ [W|U]^T, K=2560, epilogue *(1+v).
    gemm_db<128, 128, 2, 2, true><<<512, 256, 0, stream>>>(
        Aaug, BigB, out, v, 2048, 2560, 2560, 2560, 16);
}